// Round 9
// baseline (83.550 us; speedup 1.0000x reference)
//
#include <hip/hip_runtime.h>
#include <math.h>

#define BB 4
#define TT 1024
#define HH 16
#define NROWS 64    // 2*BINS table rows
#define TPAD 72     // transposed-table row pad: bank(h,idx)=(h*8+idx)%32, conflict-free
#define ROWS_PER_BLOCK 8

#define PI_F    3.14159265358979323846f
#define TWOPI_F 6.28318530717958647692f

typedef float f4 __attribute__((ext_vector_type(4)));

// Linear-stream decomposition: wave w of block (b, row-octet, plane-quad hq)
// owns plane h = hq*4+w and writes its 8 rows x 4KB = 32KB as ONE contiguous
// address stream (stores back-to-back within a row, rows adjacent).
// Table is transposed in LDS (tl_t[h][tablerow]) so the per-j lookup for a
// wave-uniform h is a scalar ds_read_b32 with zero bank conflicts:
// bank = (h*8 + idx) % 32 is bijective over idx in [0,32) and [32,64).
// Grid: 2048 blocks = 4(b) x 128(octet) x 4(hq).
__global__ __launch_bounds__(256) void QuantizedRPE_fused_kernel(
        const float* __restrict__ coords,
        const float* __restrict__ table,
        float* __restrict__ out) {
    __shared__ float tl_t[HH][TPAD];    // [h][tablerow]; rows 0..31 eta, 32..63 phi
    __shared__ float sre[BB];
    int tid = threadIdx.x;
    int lane = tid & 63;
    int w = tid >> 6;

    // ---- stage table transposed: thread t loads table row t>>2, cols (t&3)*4 ----
    {
        f4 t4 = ((const f4*)table)[tid];
        int row = tid >> 2, col = (tid & 3) * 4;
        tl_t[col + 0][row] = t4.x;
        tl_t[col + 1][row] = t4.y;
        tl_t[col + 2][row] = t4.z;
        tl_t[col + 3][row] = t4.w;
    }

    // ---- global eta range: wave w reduces batch w ----
    {
        const f4* cp4 = (const f4*)coords;
        float mx = -1e30f, mn = 1e30f;
        #pragma unroll
        for (int it = 0; it < TT / 128; ++it) {
            f4 v = cp4[(size_t)w * (TT / 2) + lane + it * 64];
            mx = fmaxf(mx, fmaxf(v.x, v.z));
            mn = fminf(mn, fminf(v.x, v.z));
        }
        #pragma unroll
        for (int m = 32; m; m >>= 1) {
            mx = fmaxf(mx, __shfl_xor(mx, m));
            mn = fminf(mn, __shfl_xor(mn, m));
        }
        if (lane == 0) sre[w] = mx - mn;
    }
    __syncthreads();
    float range = fmaxf(fmaxf(fmaxf(sre[0], sre[1]), fmaxf(sre[2], sre[3])), 1e-6f);

    int b   = blockIdx.x >> 9;
    int rem = blockIdx.x & 511;
    int i0  = (rem >> 2) * ROWS_PER_BLOCK;
    int hq  = rem & 3;
    int h   = hq * 4 + w;                 // this wave's plane
    const float* th = &tl_t[h][0];        // wave-uniform LDS base

    // j-coords for this lane's 16 j's: chunk c covers j = c*256 + lane*4 + {0..3}
    float ej[16], pj[16];
    #pragma unroll
    for (int c = 0; c < 4; ++c) {
        const f4* cp = (const f4*)(coords + (size_t)(b * TT + c * 256 + lane * 4) * 2);
        f4 c01 = cp[0];
        f4 c23 = cp[1];
        ej[c * 4 + 0] = c01.x; pj[c * 4 + 0] = c01.y;
        ej[c * 4 + 1] = c01.z; pj[c * 4 + 1] = c01.w;
        ej[c * 4 + 2] = c23.x; pj[c * 4 + 2] = c23.y;
        ej[c * 4 + 3] = c23.z; pj[c * 4 + 3] = c23.w;
    }

    #pragma unroll 1
    for (int r = 0; r < ROWS_PER_BLOCK; ++r) {
        int i = i0 + r;
        float ei  = coords[(size_t)(b * TT + i) * 2 + 0];   // block-uniform
        float pii = coords[(size_t)(b * TT + i) * 2 + 1];
        float* rowp = out + ((size_t)((b * HH + h) * TT + i)) * TT + lane * 4;

        #pragma unroll
        for (int c = 0; c < 4; ++c) {
            float v[4];
            #pragma unroll
            for (int jj = 0; jj < 4; ++jj) {
                // eta bin: same op order as reference (bit-exact, frozen)
                float re = ei - ej[c * 4 + jj];
                int be = (int)(re / range * 16.0f);
                be = min(max(be, -16), 15);
                int eidx = be + 16;                 // [0,32)
                // phi wrap: fmod + sign-fix == np.mod (exact)
                float ww = (pii - pj[c * 4 + jj]) + PI_F;
                float m = fmodf(ww, TWOPI_F);
                if (m < 0.0f) m += TWOPI_F;
                float rp = m - PI_F;
                int bp = (int)(rp / PI_F * 16.0f);
                bp = min(max(bp, -16), 15);
                int pidx = bp + 48;                 // [32,64)

                v[jj] = th[eidx] + th[pidx];        // 2x ds_read_b32, conflict-free
            }
            f4 sv = { v[0], v[1], v[2], v[3] };
            *(f4*)(rowp + c * 256) = sv;            // back-to-back same-plane stores
        }
    }
}

extern "C" void kernel_launch(void* const* d_in, const int* in_sizes, int n_in,
                              void* d_out, int out_size, void* d_ws, size_t ws_size,
                              hipStream_t stream) {
    const float* coords = (const float*)d_in[0];   // [4,1024,2] f32
    const float* table  = (const float*)d_in[1];   // [64,16]   f32
    float* out = (float*)d_out;                    // [4,16,1024,1024] f32
    (void)d_ws; (void)ws_size;

    QuantizedRPE_fused_kernel<<<BB * (TT / ROWS_PER_BLOCK) * 4, 256, 0, stream>>>(coords, table, out);
}

// Round 10
// 52.981 us; speedup vs baseline: 1.5770x; 1.5770x over previous
//
#include <hip/hip_runtime.h>
#include <math.h>

#define BB 4
#define TT 1024
#define HH 16
#define NROWS 64   // 2*BINS table rows
#define RPAD 20    // padded row floats (80 B: 16B-aligned, row-start bank period 8)
#define ROWS_PER_BLOCK 8
#define NXCD 8

#define PI_F    3.14159265358979323846f
#define TWOPI_F 6.28318530717958647692f

typedef float f4 __attribute__((ext_vector_type(4)));

// R6 structure (best: 46.4 us): fused range-reduce + table stage, 8 rows per
// block, j-major stores (1KB/wave-store, 16-plane round per row).
// This round's single change: bijective XCD-chunked blockIdx swizzle
// (grid 512, 512%8==0) so each XCD owns a contiguous output chunk.
__global__ __launch_bounds__(256) void QuantizedRPE_fused_kernel(
        const float* __restrict__ coords,
        const float* __restrict__ table,
        float* __restrict__ out) {
    __shared__ float tl[NROWS][RPAD];   // [row][h]; rows 0..31 eta, 32..63 phi
    __shared__ float sre[BB];
    int tid = threadIdx.x;
    int lane = tid & 63;
    int w = tid >> 6;

    // ---- stage table: 256 x float4 covers 64 rows x 16 floats ----
    {
        f4 t4 = ((const f4*)table)[tid];
        int row = tid >> 2, col = (tid & 3) * 4;
        *(f4*)&tl[row][col] = t4;
    }

    // ---- global eta range: wave w reduces batch w (f4 = 2 coord pairs) ----
    {
        const f4* cp4 = (const f4*)coords;
        float mx = -1e30f, mn = 1e30f;
        #pragma unroll
        for (int it = 0; it < TT / 128; ++it) {     // 512 f4 per batch / 64 lanes
            f4 v = cp4[(size_t)w * (TT / 2) + lane + it * 64];
            mx = fmaxf(mx, fmaxf(v.x, v.z));
            mn = fminf(mn, fminf(v.x, v.z));
        }
        #pragma unroll
        for (int m = 32; m; m >>= 1) {
            mx = fmaxf(mx, __shfl_xor(mx, m));
            mn = fminf(mn, __shfl_xor(mn, m));
        }
        if (lane == 0) sre[w] = mx - mn;
    }
    __syncthreads();
    float range = fmaxf(fmaxf(fmaxf(sre[0], sre[1]), fmaxf(sre[2], sre[3])), 1e-6f);

    // bijective XCD-chunked swizzle: nwg = 512 = 8 * 64
    int nwg_per_xcd = (BB * TT / ROWS_PER_BLOCK) / NXCD;      // 64
    int bid = (int)blockIdx.x;
    int swz = (bid % NXCD) * nwg_per_xcd + bid / NXCD;

    int b  = swz >> 7;
    int i0 = (swz & 127) * ROWS_PER_BLOCK;

    // j-coords: row-invariant, load once per block
    int j0 = tid * 4;
    const f4* cp = (const f4*)(coords + (size_t)(b * TT + j0) * 2);
    f4 c01 = cp[0];
    f4 c23 = cp[1];
    float ej[4] = {c01.x, c01.z, c23.x, c23.z};
    float pj[4] = {c01.y, c01.w, c23.y, c23.w};

    #pragma unroll
    for (int r = 0; r < ROWS_PER_BLOCK; ++r) {
        int i = i0 + r;
        float ei  = coords[(size_t)(b * TT + i) * 2 + 0];
        float pii = coords[(size_t)(b * TT + i) * 2 + 1];

        float s[4][16];   // s[j][h], all indices compile-time after unroll
        #pragma unroll
        for (int jj = 0; jj < 4; ++jj) {
            // eta bin: same op order as reference (bit-exact, frozen)
            float re = ei - ej[jj];
            int be = (int)(re / range * 16.0f);
            be = min(max(be, -16), 15);
            int eidx = be + 16;                 // [0,32)
            // phi wrap: fmod + sign-fix == np.mod (exact)
            float ww = (pii - pj[jj]) + PI_F;
            float m = fmodf(ww, TWOPI_F);
            if (m < 0.0f) m += TWOPI_F;
            float rp = m - PI_F;
            int bp = (int)(rp / PI_F * 16.0f);
            bp = min(max(bp, -16), 15);
            int pidx = bp + 48;                 // [32,64)

            const f4* er = (const f4*)&tl[eidx][0];   // 4x ds_read_b128
            const f4* pr = (const f4*)&tl[pidx][0];
            #pragma unroll
            for (int q = 0; q < 4; ++q) {
                f4 a = er[q];
                f4 c = pr[q];
                s[jj][q * 4 + 0] = a.x + c.x;
                s[jj][q * 4 + 1] = a.y + c.y;
                s[jj][q * 4 + 2] = a.z + c.z;
                s[jj][q * 4 + 3] = a.w + c.w;
            }
        }

        float* op = out + ((size_t)(b * HH) * TT + i) * TT + j0;
        #pragma unroll
        for (int h = 0; h < HH; ++h) {
            f4 v = {s[0][h], s[1][h], s[2][h], s[3][h]};
            *(f4*)(op + (size_t)h * TT * TT) = v;
        }
    }
}

extern "C" void kernel_launch(void* const* d_in, const int* in_sizes, int n_in,
                              void* d_out, int out_size, void* d_ws, size_t ws_size,
                              hipStream_t stream) {
    const float* coords = (const float*)d_in[0];   // [4,1024,2] f32
    const float* table  = (const float*)d_in[1];   // [64,16]   f32
    float* out = (float*)d_out;                    // [4,16,1024,1024] f32
    (void)d_ws; (void)ws_size;

    QuantizedRPE_fused_kernel<<<BB * TT / ROWS_PER_BLOCK, 256, 0, stream>>>(coords, table, out);
}

// Round 11
// 46.264 us; speedup vs baseline: 1.8059x; 1.1452x over previous
//
#include <hip/hip_runtime.h>
#include <math.h>

#define BB 4
#define TT 1024
#define HH 16
#define NROWS 64   // 2*BINS table rows
#define RPAD 20    // padded row floats (80 B: 16B-aligned, row-start bank period 8)
#define ROWS_PER_BLOCK 8

#define PI_F    3.14159265358979323846f
#define TWOPI_F 6.28318530717958647692f

typedef float f4 __attribute__((ext_vector_type(4)));

// Best variant (R6, 46.4 us = ~96% of achievable store BW).
// Fused: per-block redundant eta-range reduce + table stage, 8 output rows
// per block, j-major stores (1KB/wave-store, 16-plane round per row).
// Tested and rejected: NT stores (+14us), plane-quad decomposition (+3us),
// linear per-wave streams (+37us), XCD-chunked swizzle (+6.6us),
// split range-kernel (+6.6us).
__global__ __launch_bounds__(256) void QuantizedRPE_fused_kernel(
        const float* __restrict__ coords,
        const float* __restrict__ table,
        float* __restrict__ out) {
    __shared__ float tl[NROWS][RPAD];   // [row][h]; rows 0..31 eta, 32..63 phi
    __shared__ float sre[BB];
    int tid = threadIdx.x;
    int lane = tid & 63;
    int w = tid >> 6;

    // ---- stage table: 256 x float4 covers 64 rows x 16 floats ----
    {
        f4 t4 = ((const f4*)table)[tid];
        int row = tid >> 2, col = (tid & 3) * 4;
        *(f4*)&tl[row][col] = t4;
    }

    // ---- global eta range: wave w reduces batch w (f4 = 2 coord pairs) ----
    {
        const f4* cp4 = (const f4*)coords;
        float mx = -1e30f, mn = 1e30f;
        #pragma unroll
        for (int it = 0; it < TT / 128; ++it) {     // 512 f4 per batch / 64 lanes
            f4 v = cp4[(size_t)w * (TT / 2) + lane + it * 64];
            mx = fmaxf(mx, fmaxf(v.x, v.z));
            mn = fminf(mn, fminf(v.x, v.z));
        }
        #pragma unroll
        for (int m = 32; m; m >>= 1) {
            mx = fmaxf(mx, __shfl_xor(mx, m));
            mn = fminf(mn, __shfl_xor(mn, m));
        }
        if (lane == 0) sre[w] = mx - mn;
    }
    __syncthreads();
    float range = fmaxf(fmaxf(fmaxf(sre[0], sre[1]), fmaxf(sre[2], sre[3])), 1e-6f);

    int b  = blockIdx.x >> 7;
    int i0 = (blockIdx.x & 127) * ROWS_PER_BLOCK;

    // j-coords: row-invariant, load once per block
    int j0 = tid * 4;
    const f4* cp = (const f4*)(coords + (size_t)(b * TT + j0) * 2);
    f4 c01 = cp[0];
    f4 c23 = cp[1];
    float ej[4] = {c01.x, c01.z, c23.x, c23.z};
    float pj[4] = {c01.y, c01.w, c23.y, c23.w};

    #pragma unroll
    for (int r = 0; r < ROWS_PER_BLOCK; ++r) {
        int i = i0 + r;
        float ei  = coords[(size_t)(b * TT + i) * 2 + 0];
        float pii = coords[(size_t)(b * TT + i) * 2 + 1];

        float s[4][16];   // s[j][h], all indices compile-time after unroll
        #pragma unroll
        for (int jj = 0; jj < 4; ++jj) {
            // eta bin: same op order as reference (bit-exact, frozen)
            float re = ei - ej[jj];
            int be = (int)(re / range * 16.0f);
            be = min(max(be, -16), 15);
            int eidx = be + 16;                 // [0,32)
            // phi wrap: fmod + sign-fix == np.mod (exact)
            float ww = (pii - pj[jj]) + PI_F;
            float m = fmodf(ww, TWOPI_F);
            if (m < 0.0f) m += TWOPI_F;
            float rp = m - PI_F;
            int bp = (int)(rp / PI_F * 16.0f);
            bp = min(max(bp, -16), 15);
            int pidx = bp + 48;                 // [32,64)

            const f4* er = (const f4*)&tl[eidx][0];   // 4x ds_read_b128
            const f4* pr = (const f4*)&tl[pidx][0];
            #pragma unroll
            for (int q = 0; q < 4; ++q) {
                f4 a = er[q];
                f4 c = pr[q];
                s[jj][q * 4 + 0] = a.x + c.x;
                s[jj][q * 4 + 1] = a.y + c.y;
                s[jj][q * 4 + 2] = a.z + c.z;
                s[jj][q * 4 + 3] = a.w + c.w;
            }
        }

        float* op = out + ((size_t)(b * HH) * TT + i) * TT + j0;
        #pragma unroll
        for (int h = 0; h < HH; ++h) {
            f4 v = {s[0][h], s[1][h], s[2][h], s[3][h]};
            *(f4*)(op + (size_t)h * TT * TT) = v;
        }
    }
}

extern "C" void kernel_launch(void* const* d_in, const int* in_sizes, int n_in,
                              void* d_out, int out_size, void* d_ws, size_t ws_size,
                              hipStream_t stream) {
    const float* coords = (const float*)d_in[0];   // [4,1024,2] f32
    const float* table  = (const float*)d_in[1];   // [64,16]   f32
    float* out = (float*)d_out;                    // [4,16,1024,1024] f32
    (void)d_ws; (void)ws_size;

    QuantizedRPE_fused_kernel<<<BB * TT / ROWS_PER_BLOCK, 256, 0, stream>>>(coords, table, out);
}